// Round 12
// baseline (219.856 us; speedup 1.0000x reference)
//
#include <hip/hip_runtime.h>

// LSTM-cell (h0=c0=0) + Linear.  out = Lin(h(x @ W_ih^T + b)), f-gate dead.
// x: [65536,1024] f32 -> out: [65536,1024] f32. HBM floor ~84us total.
// R12: ATTRIBUTION ROUND — identical kernels to R11; lstm_gates launched
// TWICE (idempotent: rewrites g_h with same values; same-stream => serial).
//   R11: G + L = 163us.  R12: 2G + L = dur.  => G = dur - 163, L = 326 - dur.
// Needed because R11's rocprof top-5 was all harness fillBuffer dispatches
// (152us each @ 7TB/s — which also proves the chip does 7TB/s on linear
// writes; our 2.4TB/s is a pattern problem, not a machine cap).

typedef _Float16 f16;
typedef f16 f16x8 __attribute__((ext_vector_type(8)));
typedef float f32x4 __attribute__((ext_vector_type(4)));

#define W1S_ELEMS (32 * 10 * 64)   // f16x8 units: [ks32][gt][lane]
#define W2S_ELEMS (64 * 2 * 64)    // f16x8 units: [ct][ks2][lane]

__device__ f16x8 g_w1s[W1S_ELEMS];
__device__ f16x8 g_w2s[W2S_ELEMS];
__device__ float g_bias[160];
__device__ f16   g_h[65536L * 64];   // intermediate h (8MB)

__device__ __forceinline__ int pack_map(int j) {
    return (j < 50) ? j : (j < 150) ? (j + 50) : -1;   // skip dead f-gate rows
}

__global__ __launch_bounds__(256) void prep_kernel(
    const float* __restrict__ W_ih, const float* __restrict__ b_ih,
    const float* __restrict__ b_hh, const float* __restrict__ W_lin)
{
    int idx = blockIdx.x * 256 + threadIdx.x;
    if (idx < W1S_ELEMS) {
        int lane = idx & 63, rest = idx >> 6;
        int gt = rest % 10, ks = rest / 10;
        int prow = gt * 16 + (lane & 15);
        int oj = pack_map(prow);
        int k0 = ks * 32 + ((lane >> 4) << 3);
        f16x8 v;
        #pragma unroll
        for (int j = 0; j < 8; ++j)
            v[j] = (f16)((oj >= 0) ? W_ih[oj * 1024 + k0 + j] : 0.f);
        g_w1s[idx] = v;
    } else if (idx < W1S_ELEMS + W2S_ELEMS) {
        int i2 = idx - W1S_ELEMS;
        int lane = i2 & 63, rest = i2 >> 6;
        int ks = rest & 1, ct = rest >> 1;
        int ocol = ct * 16 + (lane & 15);
        int k0 = ks * 32 + ((lane >> 4) << 3);
        f16x8 v;
        #pragma unroll
        for (int j = 0; j < 8; ++j) {
            int k = k0 + j;
            v[j] = (f16)((k < 50) ? W_lin[ocol * 50 + k] : 0.f);
        }
        g_w2s[i2] = v;
    } else if (idx < W1S_ELEMS + W2S_ELEMS + 160) {
        int i3 = idx - (W1S_ELEMS + W2S_ELEMS);
        int oj = pack_map(i3);
        g_bias[i3] = (oj >= 0) ? (b_ih[oj] + b_hh[oj]) : 0.f;
    }
}

// rotation swizzle for the f32 gate buffer (<=2-way banks both sides)
__device__ __forceinline__ int gaddr(int row, int col) {
    int c = col + ((row & 15) << 2);
    if (c >= 160) c -= 160;
    return row * 160 + c;
}

__device__ __forceinline__ float fast_tanh(float v) {
    float t = __expf(-2.f * v);
    return (1.f - t) / (1.f + t);
}

#define GLOAD16(gp, lp) __builtin_amdgcn_global_load_lds( \
    (const __attribute__((address_space(1))) void*)(gp),  \
    (__attribute__((address_space(3))) void*)(lp), 16, 0, 0)

// ---- kernel A: x -> h (R10 phase 1 + nonlin, proven; h to g_h) -------------
__global__ __launch_bounds__(256, 4) void lstm_gates(const float* __restrict__ x)
{
    __shared__ __align__(16) char smem[40960];
    float* gs = (float*)smem;
    f16*   hs = (f16*)smem;

    const int tid  = threadIdx.x;
    const int lane = tid & 63;
    const int wv   = tid >> 6;
    const int lcol = lane & 15;
    const int l4   = lane >> 4;
    const long row0 = (long)blockIdx.x * 64;
    const int wrow = wv * 16;

    const int bid   = blockIdx.x;
    const int koff  = (bid * 5 + (bid >> 8) * 8) & 31;

    const int wt0 = (wv < 2) ? wv * 3 : 6 + (wv - 2) * 2;
    const int nw  = (wv < 2) ? 3 : 2;

    const int sw = ((lane & 7) ^ (lane >> 3)) << 2;
    const float* xsrc0 = x + (row0 + (2 * wv) * 8 + (lane >> 3)) * 1024 + sw;
    const float* xsrc1 = x + (row0 + (2 * wv + 1) * 8 + (lane >> 3)) * 1024 + sw;

    char* xs0 = smem + (2 * wv) * 1024;
    char* xs1 = smem + (2 * wv + 1) * 1024;

    #define STAGE(c, par) do {                                                 \
        const int c_ = (c);                                                    \
        const int p_ = (par);                                                  \
        GLOAD16(xsrc0 + c_ * 32, xs0 + p_ * 8192);                             \
        GLOAD16(xsrc1 + c_ * 32, xs1 + p_ * 8192);                             \
        _Pragma("unroll")                                                      \
        for (int wti = 0; wti < 3; ++wti)                                      \
            if (wti < nw)                                                      \
                GLOAD16((const f16x8*)g_w1s + c_ * 640 + (wt0 + wti) * 64 + lane, \
                        smem + 16384 + p_ * 10240 + (wt0 + wti) * 1024);       \
    } while (0)

    f32x4 acc[10];
    #pragma unroll
    for (int g = 0; g < 10; ++g) acc[g] = (f32x4){0.f, 0.f, 0.f, 0.f};

    STAGE(koff, 0);
    STAGE((koff + 1) & 31, 1);

    const int abyte = (wrow + lcol) * 128;
    const int au0 = ((2 * l4 + 0) ^ (lcol & 7)) << 4;
    const int au1 = ((2 * l4 + 1) ^ (lcol & 7)) << 4;

    for (int t = 0; t < 32; ++t) {
        if (t == 31)       asm volatile("s_waitcnt vmcnt(0)" ::: "memory");
        else if (wv < 2)   asm volatile("s_waitcnt vmcnt(5)" ::: "memory");
        else               asm volatile("s_waitcnt vmcnt(4)" ::: "memory");
        __builtin_amdgcn_sched_barrier(0);
        __builtin_amdgcn_s_barrier();

        const int par = t & 1;
        const char* ab = smem + par * 8192 + abyte;
        float4 qa = *(const float4*)(ab + au0);
        float4 qb = *(const float4*)(ab + au1);
        f16x8 af = { (f16)qa.x, (f16)qa.y, (f16)qa.z, (f16)qa.w,
                     (f16)qb.x, (f16)qb.y, (f16)qb.z, (f16)qb.w };
        const f16x8* wb = (const f16x8*)(smem + 16384 + par * 10240) + lane;
        #pragma unroll
        for (int g = 0; g < 10; ++g) {
            f16x8 bf = wb[g * 64];
            acc[g] = __builtin_amdgcn_mfma_f32_16x16x32_f16(af, bf, acc[g], 0, 0, 0);
        }

        asm volatile("s_waitcnt lgkmcnt(0)" ::: "memory");
        __builtin_amdgcn_sched_barrier(0);
        __builtin_amdgcn_s_barrier();
        if (t < 30) STAGE((t + 2 + koff) & 31, par);
    }

    // gates(+bias) -> swizzled LDS exchange
    #pragma unroll
    for (int g = 0; g < 10; ++g) {
        float bb = g_bias[g * 16 + lcol];
        #pragma unroll
        for (int r = 0; r < 4; ++r)
            gs[gaddr(wrow + l4 * 4 + r, g * 16 + lcol)] = acc[g][r] + bb;
    }
    __syncthreads();

    const int nrow = tid >> 2, sub = tid & 3;
    const int c0 = sub * 13;
    float hreg[13];
    #pragma unroll
    for (int j = 0; j < 13; ++j) {
        int c = c0 + j;
        float hv = 0.f;
        if (c < 50) {
            float iv = gs[gaddr(nrow, c)];
            float gv = gs[gaddr(nrow, 50 + c)];
            float ov = gs[gaddr(nrow, 100 + c)];
            float cv = fast_tanh(gv) / (1.f + __expf(-iv));
            hv = fast_tanh(cv) / (1.f + __expf(-ov));
        }
        hreg[j] = hv;
    }
    __syncthreads();

    #pragma unroll
    for (int j = 0; j < 13; ++j)
        hs[nrow * 72 + c0 + j] = (f16)hreg[j];
    if (sub == 3) {
        #pragma unroll
        for (int c = 52; c < 64; ++c) hs[nrow * 72 + c] = (f16)0.f;
    }
    __syncthreads();

    // h tile -> g_h (vectorized 2x16B per thread, coalesced)
    {
        const int hr = tid >> 2;                 // 0..63
        const int uu = (tid & 3) * 2;            // f16x8 unit 0,2,4,6
        f16x8 v0 = *(const f16x8*)(hs + hr * 72 + uu * 8);
        f16x8 v1 = *(const f16x8*)(hs + hr * 72 + uu * 8 + 8);
        *(f16x8*)(g_h + (row0 + hr) * 64 + uu * 8)     = v0;
        *(f16x8*)(g_h + (row0 + hr) * 64 + uu * 8 + 8) = v1;
    }
}

// ---- kernel B: h -> out (skinny GEMM K=64, write-dominated) ----------------
__global__ __launch_bounds__(256, 8) void lstm_lin(
    const float* __restrict__ blin, float* __restrict__ out)
{
    __shared__ __align__(16) f16 hs_l[32 * 72];   // padded: 144B stride, 2-way banks

    const int tid  = threadIdx.x;
    const int lane = tid & 63;
    const int wv   = tid >> 6;
    const int lcol = lane & 15;
    const int l4   = lane >> 4;
    const long r0  = (long)blockIdx.x * 32;

    {   // load h tile: 32x64 f16, one f16x8 per thread
        int row = tid >> 3, u = tid & 7;
        *(f16x8*)(hs_l + row * 72 + u * 8) =
            *(const f16x8*)(g_h + (r0 + row) * 64 + u * 8);
    }
    __syncthreads();

    f16x8 bh[2][2];
    #pragma unroll
    for (int rt = 0; rt < 2; ++rt)
        #pragma unroll
        for (int k2 = 0; k2 < 2; ++k2)
            bh[rt][k2] = *(const f16x8*)(hs_l + (rt * 16 + lcol) * 72 + k2 * 32 + l4 * 8);

    const int ct0  = wv * 16;                    // wave owns 256 out cols
    const int boff = blockIdx.x & 15;            // store-phase decorrelation
    #pragma unroll 4
    for (int i = 0; i < 16; ++i) {
        int ct = ct0 + ((i + boff) & 15);
        float4 bl = *(const float4*)(blin + ct * 16 + l4 * 4);
        const f16x8* w2b = g_w2s + ct * 128 + lane;
        f16x8 w20 = w2b[0], w21 = w2b[64];
        f32x4 o0 = { bl.x, bl.y, bl.z, bl.w };
        f32x4 o1 = o0;
        o0 = __builtin_amdgcn_mfma_f32_16x16x32_f16(w20, bh[0][0], o0, 0, 0, 0);
        o0 = __builtin_amdgcn_mfma_f32_16x16x32_f16(w21, bh[0][1], o0, 0, 0, 0);
        o1 = __builtin_amdgcn_mfma_f32_16x16x32_f16(w20, bh[1][0], o1, 0, 0, 0);
        o1 = __builtin_amdgcn_mfma_f32_16x16x32_f16(w21, bh[1][1], o1, 0, 0, 0);
        *(float4*)(out + (r0 + lcol) * 1024 + ct * 16 + l4 * 4)        = *(float4*)&o0;
        *(float4*)(out + (r0 + 16 + lcol) * 1024 + ct * 16 + l4 * 4)   = *(float4*)&o1;
    }
}

extern "C" void kernel_launch(void* const* d_in, const int* in_sizes, int n_in,
                              void* d_out, int out_size, void* d_ws, size_t ws_size,
                              hipStream_t stream) {
    const float* x     = (const float*)d_in[0];
    const float* W_ih  = (const float*)d_in[1];
    // d_in[2] = W_hh — provably unused (h_prev = 0)
    const float* b_ih  = (const float*)d_in[3];
    const float* b_hh  = (const float*)d_in[4];
    const float* W_lin = (const float*)d_in[5];
    const float* b_lin = (const float*)d_in[6];
    float* out = (float*)d_out;

    int prep_total = W1S_ELEMS + W2S_ELEMS + 160;
    prep_kernel<<<(prep_total + 255) / 256, 256, 0, stream>>>(
        W_ih, b_ih, b_hh, W_lin);

    // ATTRIBUTION: gates launched twice (idempotent). 2G + L = dur;
    // with R11's G + L = 163us  =>  G = dur - 163, L = 326 - dur.
    lstm_gates<<<1024, 256, 0, stream>>>(x);
    lstm_gates<<<1024, 256, 0, stream>>>(x);
    lstm_lin<<<2048, 256, 0, stream>>>(b_lin, out);
}

// Round 13
// 157.553 us; speedup vs baseline: 1.3954x; 1.3954x over previous
//
#include <hip/hip_runtime.h>

// LSTM-cell (h0=c0=0) + Linear.  out = Lin(h(x @ W_ih^T + b)), f-gate dead.
// x: [65536,1024] f32 -> out: [65536,1024] f32. HBM floor ~84us total.
// R13: R12 attribution => G=57us (gates, near floor), L=107us (lin, 2.4x floor).
// Fill kernel does 7TB/s linear writes at 10% occupancy => stores need PATTERN.
// lstm_lin's old stores: 16 rows x 64B per instruction at 4KB stride => DRAM
// page-locality collapse. Fix: LDS-staged store transpose — MFMA fragments ->
// XOR-swizzled 32KB LDS tile -> copy phase streams full 4KB rows linearly
// (block slab = 16 rows = 64KB contiguous, written in 2 half-passes).
// lstm_gates unchanged (R10-proven), single launch.

typedef _Float16 f16;
typedef f16 f16x8 __attribute__((ext_vector_type(8)));
typedef float f32x4 __attribute__((ext_vector_type(4)));

#define W1S_ELEMS (32 * 10 * 64)   // f16x8 units: [ks32][gt][lane]
#define W2S_ELEMS (64 * 2 * 64)    // f16x8 units: [ct][ks2][lane]

__device__ f16x8 g_w1s[W1S_ELEMS];
__device__ f16x8 g_w2s[W2S_ELEMS];
__device__ float g_bias[160];
__device__ f16   g_h[65536L * 64];   // intermediate h (8MB)

__device__ __forceinline__ int pack_map(int j) {
    return (j < 50) ? j : (j < 150) ? (j + 50) : -1;   // skip dead f-gate rows
}

__global__ __launch_bounds__(256) void prep_kernel(
    const float* __restrict__ W_ih, const float* __restrict__ b_ih,
    const float* __restrict__ b_hh, const float* __restrict__ W_lin)
{
    int idx = blockIdx.x * 256 + threadIdx.x;
    if (idx < W1S_ELEMS) {
        int lane = idx & 63, rest = idx >> 6;
        int gt = rest % 10, ks = rest / 10;
        int prow = gt * 16 + (lane & 15);
        int oj = pack_map(prow);
        int k0 = ks * 32 + ((lane >> 4) << 3);
        f16x8 v;
        #pragma unroll
        for (int j = 0; j < 8; ++j)
            v[j] = (f16)((oj >= 0) ? W_ih[oj * 1024 + k0 + j] : 0.f);
        g_w1s[idx] = v;
    } else if (idx < W1S_ELEMS + W2S_ELEMS) {
        int i2 = idx - W1S_ELEMS;
        int lane = i2 & 63, rest = i2 >> 6;
        int ks = rest & 1, ct = rest >> 1;
        int ocol = ct * 16 + (lane & 15);
        int k0 = ks * 32 + ((lane >> 4) << 3);
        f16x8 v;
        #pragma unroll
        for (int j = 0; j < 8; ++j) {
            int k = k0 + j;
            v[j] = (f16)((k < 50) ? W_lin[ocol * 50 + k] : 0.f);
        }
        g_w2s[i2] = v;
    } else if (idx < W1S_ELEMS + W2S_ELEMS + 160) {
        int i3 = idx - (W1S_ELEMS + W2S_ELEMS);
        int oj = pack_map(i3);
        g_bias[i3] = (oj >= 0) ? (b_ih[oj] + b_hh[oj]) : 0.f;
    }
}

// rotation swizzle for the f32 gate buffer (<=2-way banks both sides)
__device__ __forceinline__ int gaddr(int row, int col) {
    int c = col + ((row & 15) << 2);
    if (c >= 160) c -= 160;
    return row * 160 + c;
}

__device__ __forceinline__ float fast_tanh(float v) {
    float t = __expf(-2.f * v);
    return (1.f - t) / (1.f + t);
}

#define GLOAD16(gp, lp) __builtin_amdgcn_global_load_lds( \
    (const __attribute__((address_space(1))) void*)(gp),  \
    (__attribute__((address_space(3))) void*)(lp), 16, 0, 0)

// ---- kernel A: x -> h (R10 phase 1 + nonlin, proven; h to g_h) -------------
__global__ __launch_bounds__(256, 4) void lstm_gates(const float* __restrict__ x)
{
    __shared__ __align__(16) char smem[40960];
    float* gs = (float*)smem;
    f16*   hs = (f16*)smem;

    const int tid  = threadIdx.x;
    const int lane = tid & 63;
    const int wv   = tid >> 6;
    const int lcol = lane & 15;
    const int l4   = lane >> 4;
    const long row0 = (long)blockIdx.x * 64;
    const int wrow = wv * 16;

    const int bid   = blockIdx.x;
    const int koff  = (bid * 5 + (bid >> 8) * 8) & 31;

    const int wt0 = (wv < 2) ? wv * 3 : 6 + (wv - 2) * 2;
    const int nw  = (wv < 2) ? 3 : 2;

    const int sw = ((lane & 7) ^ (lane >> 3)) << 2;
    const float* xsrc0 = x + (row0 + (2 * wv) * 8 + (lane >> 3)) * 1024 + sw;
    const float* xsrc1 = x + (row0 + (2 * wv + 1) * 8 + (lane >> 3)) * 1024 + sw;

    char* xs0 = smem + (2 * wv) * 1024;
    char* xs1 = smem + (2 * wv + 1) * 1024;

    #define STAGE(c, par) do {                                                 \
        const int c_ = (c);                                                    \
        const int p_ = (par);                                                  \
        GLOAD16(xsrc0 + c_ * 32, xs0 + p_ * 8192);                             \
        GLOAD16(xsrc1 + c_ * 32, xs1 + p_ * 8192);                             \
        _Pragma("unroll")                                                      \
        for (int wti = 0; wti < 3; ++wti)                                      \
            if (wti < nw)                                                      \
                GLOAD16((const f16x8*)g_w1s + c_ * 640 + (wt0 + wti) * 64 + lane, \
                        smem + 16384 + p_ * 10240 + (wt0 + wti) * 1024);       \
    } while (0)

    f32x4 acc[10];
    #pragma unroll
    for (int g = 0; g < 10; ++g) acc[g] = (f32x4){0.f, 0.f, 0.f, 0.f};

    STAGE(koff, 0);
    STAGE((koff + 1) & 31, 1);

    const int abyte = (wrow + lcol) * 128;
    const int au0 = ((2 * l4 + 0) ^ (lcol & 7)) << 4;
    const int au1 = ((2 * l4 + 1) ^ (lcol & 7)) << 4;

    for (int t = 0; t < 32; ++t) {
        if (t == 31)       asm volatile("s_waitcnt vmcnt(0)" ::: "memory");
        else if (wv < 2)   asm volatile("s_waitcnt vmcnt(5)" ::: "memory");
        else               asm volatile("s_waitcnt vmcnt(4)" ::: "memory");
        __builtin_amdgcn_sched_barrier(0);
        __builtin_amdgcn_s_barrier();

        const int par = t & 1;
        const char* ab = smem + par * 8192 + abyte;
        float4 qa = *(const float4*)(ab + au0);
        float4 qb = *(const float4*)(ab + au1);
        f16x8 af = { (f16)qa.x, (f16)qa.y, (f16)qa.z, (f16)qa.w,
                     (f16)qb.x, (f16)qb.y, (f16)qb.z, (f16)qb.w };
        const f16x8* wb = (const f16x8*)(smem + 16384 + par * 10240) + lane;
        #pragma unroll
        for (int g = 0; g < 10; ++g) {
            f16x8 bf = wb[g * 64];
            acc[g] = __builtin_amdgcn_mfma_f32_16x16x32_f16(af, bf, acc[g], 0, 0, 0);
        }

        asm volatile("s_waitcnt lgkmcnt(0)" ::: "memory");
        __builtin_amdgcn_sched_barrier(0);
        __builtin_amdgcn_s_barrier();
        if (t < 30) STAGE((t + 2 + koff) & 31, par);
    }

    // gates(+bias) -> swizzled LDS exchange
    #pragma unroll
    for (int g = 0; g < 10; ++g) {
        float bb = g_bias[g * 16 + lcol];
        #pragma unroll
        for (int r = 0; r < 4; ++r)
            gs[gaddr(wrow + l4 * 4 + r, g * 16 + lcol)] = acc[g][r] + bb;
    }
    __syncthreads();

    const int nrow = tid >> 2, sub = tid & 3;
    const int c0 = sub * 13;
    float hreg[13];
    #pragma unroll
    for (int j = 0; j < 13; ++j) {
        int c = c0 + j;
        float hv = 0.f;
        if (c < 50) {
            float iv = gs[gaddr(nrow, c)];
            float gv = gs[gaddr(nrow, 50 + c)];
            float ov = gs[gaddr(nrow, 100 + c)];
            float cv = fast_tanh(gv) / (1.f + __expf(-iv));
            hv = fast_tanh(cv) / (1.f + __expf(-ov));
        }
        hreg[j] = hv;
    }
    __syncthreads();

    #pragma unroll
    for (int j = 0; j < 13; ++j)
        hs[nrow * 72 + c0 + j] = (f16)hreg[j];
    if (sub == 3) {
        #pragma unroll
        for (int c = 52; c < 64; ++c) hs[nrow * 72 + c] = (f16)0.f;
    }
    __syncthreads();

    // h tile -> g_h (vectorized 2x16B per thread, coalesced 8KB linear)
    {
        const int hr = tid >> 2;                 // 0..63
        const int uu = (tid & 3) * 2;            // f16x8 unit 0,2,4,6
        f16x8 v0 = *(const f16x8*)(hs + hr * 72 + uu * 8);
        f16x8 v1 = *(const f16x8*)(hs + hr * 72 + uu * 8 + 8);
        *(f16x8*)(g_h + (row0 + hr) * 64 + uu * 8)     = v0;
        *(f16x8*)(g_h + (row0 + hr) * 64 + uu * 8 + 8) = v1;
    }
}

// ---- kernel B v3: h -> out with LDS-staged LINEAR stores --------------------
// 16 rows/block (grid 4096). MFMA fragments -> swizzled LDS tile; copy phase
// writes full 4KB rows (block slab 64KB contiguous), 2 half-passes of 512 cols.
__global__ __launch_bounds__(256, 4) void lstm_lin(
    const float* __restrict__ blin, float* __restrict__ out)
{
    __shared__ __align__(16) f16 hs_l[16 * 72];     // 2304B
    __shared__ __align__(16) float ls[16 * 512];    // 32KB staging (one half)

    const int tid  = threadIdx.x;
    const int lane = tid & 63;
    const int wv   = tid >> 6;
    const int lcol = lane & 15;
    const int l4   = lane >> 4;
    const long r0  = (long)blockIdx.x * 16;

    if (tid < 128) {   // load h tile 16x64 f16 (2KB linear)
        int row = tid >> 3, u = tid & 7;
        *(f16x8*)(hs_l + row * 72 + u * 8) =
            *(const f16x8*)(g_h + (r0 + row) * 64 + u * 8);
    }
    __syncthreads();

    f16x8 bh0 = *(const f16x8*)(hs_l + lcol * 72 + l4 * 8);
    f16x8 bh1 = *(const f16x8*)(hs_l + lcol * 72 + 32 + l4 * 8);

    #pragma unroll
    for (int half = 0; half < 2; ++half) {
        // MFMA: each wave 8 col-tiles; D lane = (row=lcol, cols 4*l4+r of tile)
        #pragma unroll
        for (int i = 0; i < 8; ++i) {
            int ct = half * 32 + wv * 8 + i;
            float4 bl = *(const float4*)(blin + ct * 16 + l4 * 4);
            f32x4 o = { bl.x, bl.y, bl.z, bl.w };
            const f16x8* w2b = g_w2s + ct * 128 + lane;
            o = __builtin_amdgcn_mfma_f32_16x16x32_f16(w2b[0],  bh0, o, 0, 0, 0);
            o = __builtin_amdgcn_mfma_f32_16x16x32_f16(w2b[64], bh1, o, 0, 0, 0);
            int u = (wv * 8 + i) * 4 + l4;           // float4-unit within half-row
            *(f32x4*)(ls + lcol * 512 + ((u ^ (lcol & 7)) << 2)) = o;
        }
        __syncthreads();
        // copy: 16 rows x 2KB -> linear full-width stores (4KB/iter per block)
        #pragma unroll
        for (int it = 0; it < 8; ++it) {
            int row = it * 2 + (tid >> 7);
            int u = tid & 127;
            float4 v = *(const float4*)(ls + row * 512 + ((u ^ (row & 7)) << 2));
            *(float4*)(out + (r0 + row) * 1024 + half * 512 + u * 4) = v;
        }
        __syncthreads();
    }
}

extern "C" void kernel_launch(void* const* d_in, const int* in_sizes, int n_in,
                              void* d_out, int out_size, void* d_ws, size_t ws_size,
                              hipStream_t stream) {
    const float* x     = (const float*)d_in[0];
    const float* W_ih  = (const float*)d_in[1];
    // d_in[2] = W_hh — provably unused (h_prev = 0)
    const float* b_ih  = (const float*)d_in[3];
    const float* b_hh  = (const float*)d_in[4];
    const float* W_lin = (const float*)d_in[5];
    const float* b_lin = (const float*)d_in[6];
    float* out = (float*)d_out;

    int prep_total = W1S_ELEMS + W2S_ELEMS + 160;
    prep_kernel<<<(prep_total + 255) / 256, 256, 0, stream>>>(
        W_ih, b_ih, b_hh, W_lin);

    lstm_gates<<<1024, 256, 0, stream>>>(x);
    lstm_lin<<<4096, 256, 0, stream>>>(b_lin, out);
}

// Round 14
// 149.170 us; speedup vs baseline: 1.4739x; 1.0562x over previous
//
#include <hip/hip_runtime.h>

// LSTM-cell (h0=c0=0) + Linear.  out = Lin(h(x @ W_ih^T + b)), f-gate dead.
// x: [65536,1024] f32 -> out: [65536,1024] f32. HBM floor ~84us total.
// R14: store-pattern theory falsified (R13: 2KB-linear stores only 107->100us).
// Fill does 7TB/s @10% occupancy => stores need sustained ISSUE, not pattern.
// Old lin: 4096 micro-blocks, W2 (128KB) re-read per block through a thrashed
// L2, 4 barriers around tiny store bursts => low store duty cycle.
// lin v4: 256 blocks x 1024 thr (16 waves, 1/CU, fully resident); W2 frags +
// bias REGISTER-RESIDENT per wave (loaded once); per 16-row tile: MFMA ->
// swizzled 64KB LDS -> each wave streams ONE FULL 4KB out row (4x1KB stores);
// h dbuf staged under copy. Block slab = 256 rows = 1MB contiguous.
// gates unchanged (R10-proven).

typedef _Float16 f16;
typedef f16 f16x8 __attribute__((ext_vector_type(8)));
typedef float f32x4 __attribute__((ext_vector_type(4)));

#define W1S_ELEMS (32 * 10 * 64)   // f16x8 units: [ks32][gt][lane]
#define W2S_ELEMS (64 * 2 * 64)    // f16x8 units: [ct][ks2][lane]

__device__ f16x8 g_w1s[W1S_ELEMS];
__device__ f16x8 g_w2s[W2S_ELEMS];
__device__ float g_bias[160];
__device__ f16   g_h[65536L * 64];   // intermediate h (8MB)

__device__ __forceinline__ int pack_map(int j) {
    return (j < 50) ? j : (j < 150) ? (j + 50) : -1;   // skip dead f-gate rows
}

__global__ __launch_bounds__(256) void prep_kernel(
    const float* __restrict__ W_ih, const float* __restrict__ b_ih,
    const float* __restrict__ b_hh, const float* __restrict__ W_lin)
{
    int idx = blockIdx.x * 256 + threadIdx.x;
    if (idx < W1S_ELEMS) {
        int lane = idx & 63, rest = idx >> 6;
        int gt = rest % 10, ks = rest / 10;
        int prow = gt * 16 + (lane & 15);
        int oj = pack_map(prow);
        int k0 = ks * 32 + ((lane >> 4) << 3);
        f16x8 v;
        #pragma unroll
        for (int j = 0; j < 8; ++j)
            v[j] = (f16)((oj >= 0) ? W_ih[oj * 1024 + k0 + j] : 0.f);
        g_w1s[idx] = v;
    } else if (idx < W1S_ELEMS + W2S_ELEMS) {
        int i2 = idx - W1S_ELEMS;
        int lane = i2 & 63, rest = i2 >> 6;
        int ks = rest & 1, ct = rest >> 1;
        int ocol = ct * 16 + (lane & 15);
        int k0 = ks * 32 + ((lane >> 4) << 3);
        f16x8 v;
        #pragma unroll
        for (int j = 0; j < 8; ++j) {
            int k = k0 + j;
            v[j] = (f16)((k < 50) ? W_lin[ocol * 50 + k] : 0.f);
        }
        g_w2s[i2] = v;
    } else if (idx < W1S_ELEMS + W2S_ELEMS + 160) {
        int i3 = idx - (W1S_ELEMS + W2S_ELEMS);
        int oj = pack_map(i3);
        g_bias[i3] = (oj >= 0) ? (b_ih[oj] + b_hh[oj]) : 0.f;
    }
}

// rotation swizzle for the f32 gate buffer (<=2-way banks both sides)
__device__ __forceinline__ int gaddr(int row, int col) {
    int c = col + ((row & 15) << 2);
    if (c >= 160) c -= 160;
    return row * 160 + c;
}

__device__ __forceinline__ float fast_tanh(float v) {
    float t = __expf(-2.f * v);
    return (1.f - t) / (1.f + t);
}

#define GLOAD16(gp, lp) __builtin_amdgcn_global_load_lds( \
    (const __attribute__((address_space(1))) void*)(gp),  \
    (__attribute__((address_space(3))) void*)(lp), 16, 0, 0)

// ---- kernel A: x -> h (R10 phase 1 + nonlin, proven; h to g_h) -------------
__global__ __launch_bounds__(256, 4) void lstm_gates(const float* __restrict__ x)
{
    __shared__ __align__(16) char smem[40960];
    float* gs = (float*)smem;
    f16*   hs = (f16*)smem;

    const int tid  = threadIdx.x;
    const int lane = tid & 63;
    const int wv   = tid >> 6;
    const int lcol = lane & 15;
    const int l4   = lane >> 4;
    const long row0 = (long)blockIdx.x * 64;
    const int wrow = wv * 16;

    const int bid   = blockIdx.x;
    const int koff  = (bid * 5 + (bid >> 8) * 8) & 31;

    const int wt0 = (wv < 2) ? wv * 3 : 6 + (wv - 2) * 2;
    const int nw  = (wv < 2) ? 3 : 2;

    const int sw = ((lane & 7) ^ (lane >> 3)) << 2;
    const float* xsrc0 = x + (row0 + (2 * wv) * 8 + (lane >> 3)) * 1024 + sw;
    const float* xsrc1 = x + (row0 + (2 * wv + 1) * 8 + (lane >> 3)) * 1024 + sw;

    char* xs0 = smem + (2 * wv) * 1024;
    char* xs1 = smem + (2 * wv + 1) * 1024;

    #define STAGE(c, par) do {                                                 \
        const int c_ = (c);                                                    \
        const int p_ = (par);                                                  \
        GLOAD16(xsrc0 + c_ * 32, xs0 + p_ * 8192);                             \
        GLOAD16(xsrc1 + c_ * 32, xs1 + p_ * 8192);                             \
        _Pragma("unroll")                                                      \
        for (int wti = 0; wti < 3; ++wti)                                      \
            if (wti < nw)                                                      \
                GLOAD16((const f16x8*)g_w1s + c_ * 640 + (wt0 + wti) * 64 + lane, \
                        smem + 16384 + p_ * 10240 + (wt0 + wti) * 1024);       \
    } while (0)

    f32x4 acc[10];
    #pragma unroll
    for (int g = 0; g < 10; ++g) acc[g] = (f32x4){0.f, 0.f, 0.f, 0.f};

    STAGE(koff, 0);
    STAGE((koff + 1) & 31, 1);

    const int abyte = (wrow + lcol) * 128;
    const int au0 = ((2 * l4 + 0) ^ (lcol & 7)) << 4;
    const int au1 = ((2 * l4 + 1) ^ (lcol & 7)) << 4;

    for (int t = 0; t < 32; ++t) {
        if (t == 31)       asm volatile("s_waitcnt vmcnt(0)" ::: "memory");
        else if (wv < 2)   asm volatile("s_waitcnt vmcnt(5)" ::: "memory");
        else               asm volatile("s_waitcnt vmcnt(4)" ::: "memory");
        __builtin_amdgcn_sched_barrier(0);
        __builtin_amdgcn_s_barrier();

        const int par = t & 1;
        const char* ab = smem + par * 8192 + abyte;
        float4 qa = *(const float4*)(ab + au0);
        float4 qb = *(const float4*)(ab + au1);
        f16x8 af = { (f16)qa.x, (f16)qa.y, (f16)qa.z, (f16)qa.w,
                     (f16)qb.x, (f16)qb.y, (f16)qb.z, (f16)qb.w };
        const f16x8* wb = (const f16x8*)(smem + 16384 + par * 10240) + lane;
        #pragma unroll
        for (int g = 0; g < 10; ++g) {
            f16x8 bf = wb[g * 64];
            acc[g] = __builtin_amdgcn_mfma_f32_16x16x32_f16(af, bf, acc[g], 0, 0, 0);
        }

        asm volatile("s_waitcnt lgkmcnt(0)" ::: "memory");
        __builtin_amdgcn_sched_barrier(0);
        __builtin_amdgcn_s_barrier();
        if (t < 30) STAGE((t + 2 + koff) & 31, par);
    }

    // gates(+bias) -> swizzled LDS exchange
    #pragma unroll
    for (int g = 0; g < 10; ++g) {
        float bb = g_bias[g * 16 + lcol];
        #pragma unroll
        for (int r = 0; r < 4; ++r)
            gs[gaddr(wrow + l4 * 4 + r, g * 16 + lcol)] = acc[g][r] + bb;
    }
    __syncthreads();

    const int nrow = tid >> 2, sub = tid & 3;
    const int c0 = sub * 13;
    float hreg[13];
    #pragma unroll
    for (int j = 0; j < 13; ++j) {
        int c = c0 + j;
        float hv = 0.f;
        if (c < 50) {
            float iv = gs[gaddr(nrow, c)];
            float gv = gs[gaddr(nrow, 50 + c)];
            float ov = gs[gaddr(nrow, 100 + c)];
            float cv = fast_tanh(gv) / (1.f + __expf(-iv));
            hv = fast_tanh(cv) / (1.f + __expf(-ov));
        }
        hreg[j] = hv;
    }
    __syncthreads();

    #pragma unroll
    for (int j = 0; j < 13; ++j)
        hs[nrow * 72 + c0 + j] = (f16)hreg[j];
    if (sub == 3) {
        #pragma unroll
        for (int c = 52; c < 64; ++c) hs[nrow * 72 + c] = (f16)0.f;
    }
    __syncthreads();

    // h tile -> g_h (vectorized 2x16B per thread, coalesced 8KB linear)
    {
        const int hr = tid >> 2;                 // 0..63
        const int uu = (tid & 3) * 2;            // f16x8 unit 0,2,4,6
        f16x8 v0 = *(const f16x8*)(hs + hr * 72 + uu * 8);
        f16x8 v1 = *(const f16x8*)(hs + hr * 72 + uu * 8 + 8);
        *(f16x8*)(g_h + (row0 + hr) * 64 + uu * 8)     = v0;
        *(f16x8*)(g_h + (row0 + hr) * 64 + uu * 8 + 8) = v1;
    }
}

// ---- kernel B v4: h -> out; W2 register-resident, fill-like streaming stores
// 256 blocks x 1024 threads (16 waves). Block = 256 rows = 1MB out slab.
// Wave owns 4 col-tiles (W2 frags in 32 VGPR, loaded once). Per 16-row tile:
// MFMA -> swizzled 64KB LDS -> wave streams ONE full 4KB row (4x1KB stores).
__global__ __launch_bounds__(1024) void lstm_lin(
    const float* __restrict__ blin, float* __restrict__ out)
{
    __shared__ __align__(16) float ls[16 * 1024];      // 64KB out-tile staging
    __shared__ __align__(16) f16 hs_l[2][16 * 72];     // h tile double buffer

    const int tid  = threadIdx.x;
    const int lane = tid & 63;
    const int wv   = tid >> 6;        // 0..15
    const int lcol = lane & 15;
    const int l4   = lane >> 4;
    const long r0  = (long)blockIdx.x * 256;

    // per-wave register-resident W2 fragments + bias (loaded ONCE)
    f16x8 w2r0[4], w2r1[4];
    float4 blr[4];
    #pragma unroll
    for (int i = 0; i < 4; ++i) {
        int ct = wv * 4 + i;
        w2r0[i] = g_w2s[ct * 128 + lane];
        w2r1[i] = g_w2s[ct * 128 + 64 + lane];
        blr[i]  = *(const float4*)(blin + ct * 16 + l4 * 4);
    }

    // stage h tile 0
    if (tid < 128) {
        int row = tid >> 3, u = tid & 7;
        *(f16x8*)(&hs_l[0][row * 72 + u * 8]) =
            *(const f16x8*)(g_h + (r0 + row) * 64 + u * 8);
    }
    __syncthreads();

    for (int rt = 0; rt < 16; ++rt) {
        const int cur = rt & 1;
        f16x8 bh0 = *(const f16x8*)(&hs_l[cur][lcol * 72 + l4 * 8]);
        f16x8 bh1 = *(const f16x8*)(&hs_l[cur][lcol * 72 + 32 + l4 * 8]);
        #pragma unroll
        for (int i = 0; i < 4; ++i) {
            int ct = wv * 4 + i;
            f32x4 o = { blr[i].x, blr[i].y, blr[i].z, blr[i].w };
            o = __builtin_amdgcn_mfma_f32_16x16x32_f16(w2r0[i], bh0, o, 0, 0, 0);
            o = __builtin_amdgcn_mfma_f32_16x16x32_f16(w2r1[i], bh1, o, 0, 0, 0);
            // D lane: out[row=lcol][ct*16 + l4*4 + r]; unit = ct*4+l4 (16B)
            int u = (ct * 4 + l4) ^ (lcol & 7);          // bank swizzle
            *(f32x4*)(ls + lcol * 1024 + u * 4) = o;
        }
        __syncthreads();
        if (rt < 15 && tid < 128) {   // stage next h tile under the copy phase
            int row = tid >> 3, u = tid & 7;
            *(f16x8*)(&hs_l[cur ^ 1][row * 72 + u * 8]) =
                *(const f16x8*)(g_h + (r0 + (rt + 1) * 16 + row) * 64 + u * 8);
        }
        {   // copy: wave wv streams its full 4KB row as 4 x 1KB linear stores
            float* orow = out + (r0 + rt * 16 + wv) * 1024;
            #pragma unroll
            for (int j = 0; j < 4; ++j) {
                int u = (j * 64 + lane) ^ (wv & 7);
                f32x4 v = *(const f32x4*)(ls + wv * 1024 + u * 4);
                *(f32x4*)(orow + j * 256 + lane * 4) = v;
            }
        }
        __syncthreads();
    }
}

extern "C" void kernel_launch(void* const* d_in, const int* in_sizes, int n_in,
                              void* d_out, int out_size, void* d_ws, size_t ws_size,
                              hipStream_t stream) {
    const float* x     = (const float*)d_in[0];
    const float* W_ih  = (const float*)d_in[1];
    // d_in[2] = W_hh — provably unused (h_prev = 0)
    const float* b_ih  = (const float*)d_in[3];
    const float* b_hh  = (const float*)d_in[4];
    const float* W_lin = (const float*)d_in[5];
    const float* b_lin = (const float*)d_in[6];
    float* out = (float*)d_out;

    int prep_total = W1S_ELEMS + W2S_ELEMS + 160;
    prep_kernel<<<(prep_total + 255) / 256, 256, 0, stream>>>(
        W_ih, b_ih, b_hh, W_lin);

    lstm_gates<<<1024, 256, 0, stream>>>(x);
    lstm_lin<<<256, 1024, 0, stream>>>(b_lin, out);
}

// Round 15
// 114.027 us; speedup vs baseline: 1.9281x; 1.3082x over previous
//
#include <hip/hip_runtime.h>

// LSTM-cell (h0=c0=0) + Linear.  out = Lin(h(x @ W_ih^T + b)), f-gate dead.
// x: [65536,1024] f32 -> out: [65536,1024] f32.
// R15 = R14 + ONE change: lin's out stores are NONTEMPORAL.
//   Evidence: three structurally different lin kernels (scattered stores,
//   LDS-transposed 4KB rows, register-W2 + 64KB contiguous block slabs) all
//   cap at ~2.9TB/s write; rocclr fill (memset, nt stores) does 7TB/s at 10%
//   occupancy. 256MB one-shot write stream through the L2/L3 allocate path
//   thrashes both caches (4MB/XCD L2!) and is the one shared invariant.
//   __builtin_nontemporal_store => global_store_dwordx4 nt (no allocation).
// gates unchanged (R10-proven). lin layout/barriers identical to R14.

typedef _Float16 f16;
typedef f16 f16x8 __attribute__((ext_vector_type(8)));
typedef float f32x4 __attribute__((ext_vector_type(4)));

#define W1S_ELEMS (32 * 10 * 64)   // f16x8 units: [ks32][gt][lane]
#define W2S_ELEMS (64 * 2 * 64)    // f16x8 units: [ct][ks2][lane]

__device__ f16x8 g_w1s[W1S_ELEMS];
__device__ f16x8 g_w2s[W2S_ELEMS];
__device__ float g_bias[160];
__device__ f16   g_h[65536L * 64];   // intermediate h (8MB)

__device__ __forceinline__ int pack_map(int j) {
    return (j < 50) ? j : (j < 150) ? (j + 50) : -1;   // skip dead f-gate rows
}

__global__ __launch_bounds__(256) void prep_kernel(
    const float* __restrict__ W_ih, const float* __restrict__ b_ih,
    const float* __restrict__ b_hh, const float* __restrict__ W_lin)
{
    int idx = blockIdx.x * 256 + threadIdx.x;
    if (idx < W1S_ELEMS) {
        int lane = idx & 63, rest = idx >> 6;
        int gt = rest % 10, ks = rest / 10;
        int prow = gt * 16 + (lane & 15);
        int oj = pack_map(prow);
        int k0 = ks * 32 + ((lane >> 4) << 3);
        f16x8 v;
        #pragma unroll
        for (int j = 0; j < 8; ++j)
            v[j] = (f16)((oj >= 0) ? W_ih[oj * 1024 + k0 + j] : 0.f);
        g_w1s[idx] = v;
    } else if (idx < W1S_ELEMS + W2S_ELEMS) {
        int i2 = idx - W1S_ELEMS;
        int lane = i2 & 63, rest = i2 >> 6;
        int ks = rest & 1, ct = rest >> 1;
        int ocol = ct * 16 + (lane & 15);
        int k0 = ks * 32 + ((lane >> 4) << 3);
        f16x8 v;
        #pragma unroll
        for (int j = 0; j < 8; ++j) {
            int k = k0 + j;
            v[j] = (f16)((k < 50) ? W_lin[ocol * 50 + k] : 0.f);
        }
        g_w2s[i2] = v;
    } else if (idx < W1S_ELEMS + W2S_ELEMS + 160) {
        int i3 = idx - (W1S_ELEMS + W2S_ELEMS);
        int oj = pack_map(i3);
        g_bias[i3] = (oj >= 0) ? (b_ih[oj] + b_hh[oj]) : 0.f;
    }
}

// rotation swizzle for the f32 gate buffer (<=2-way banks both sides)
__device__ __forceinline__ int gaddr(int row, int col) {
    int c = col + ((row & 15) << 2);
    if (c >= 160) c -= 160;
    return row * 160 + c;
}

__device__ __forceinline__ float fast_tanh(float v) {
    float t = __expf(-2.f * v);
    return (1.f - t) / (1.f + t);
}

#define GLOAD16(gp, lp) __builtin_amdgcn_global_load_lds( \
    (const __attribute__((address_space(1))) void*)(gp),  \
    (__attribute__((address_space(3))) void*)(lp), 16, 0, 0)

// ---- kernel A: x -> h (R10 phase 1 + nonlin, proven; h to g_h) -------------
__global__ __launch_bounds__(256, 4) void lstm_gates(const float* __restrict__ x)
{
    __shared__ __align__(16) char smem[40960];
    float* gs = (float*)smem;
    f16*   hs = (f16*)smem;

    const int tid  = threadIdx.x;
    const int lane = tid & 63;
    const int wv   = tid >> 6;
    const int lcol = lane & 15;
    const int l4   = lane >> 4;
    const long row0 = (long)blockIdx.x * 64;
    const int wrow = wv * 16;

    const int bid   = blockIdx.x;
    const int koff  = (bid * 5 + (bid >> 8) * 8) & 31;

    const int wt0 = (wv < 2) ? wv * 3 : 6 + (wv - 2) * 2;
    const int nw  = (wv < 2) ? 3 : 2;

    const int sw = ((lane & 7) ^ (lane >> 3)) << 2;
    const float* xsrc0 = x + (row0 + (2 * wv) * 8 + (lane >> 3)) * 1024 + sw;
    const float* xsrc1 = x + (row0 + (2 * wv + 1) * 8 + (lane >> 3)) * 1024 + sw;

    char* xs0 = smem + (2 * wv) * 1024;
    char* xs1 = smem + (2 * wv + 1) * 1024;

    #define STAGE(c, par) do {                                                 \
        const int c_ = (c);                                                    \
        const int p_ = (par);                                                  \
        GLOAD16(xsrc0 + c_ * 32, xs0 + p_ * 8192);                             \
        GLOAD16(xsrc1 + c_ * 32, xs1 + p_ * 8192);                             \
        _Pragma("unroll")                                                      \
        for (int wti = 0; wti < 3; ++wti)                                      \
            if (wti < nw)                                                      \
                GLOAD16((const f16x8*)g_w1s + c_ * 640 + (wt0 + wti) * 64 + lane, \
                        smem + 16384 + p_ * 10240 + (wt0 + wti) * 1024);       \
    } while (0)

    f32x4 acc[10];
    #pragma unroll
    for (int g = 0; g < 10; ++g) acc[g] = (f32x4){0.f, 0.f, 0.f, 0.f};

    STAGE(koff, 0);
    STAGE((koff + 1) & 31, 1);

    const int abyte = (wrow + lcol) * 128;
    const int au0 = ((2 * l4 + 0) ^ (lcol & 7)) << 4;
    const int au1 = ((2 * l4 + 1) ^ (lcol & 7)) << 4;

    for (int t = 0; t < 32; ++t) {
        if (t == 31)       asm volatile("s_waitcnt vmcnt(0)" ::: "memory");
        else if (wv < 2)   asm volatile("s_waitcnt vmcnt(5)" ::: "memory");
        else               asm volatile("s_waitcnt vmcnt(4)" ::: "memory");
        __builtin_amdgcn_sched_barrier(0);
        __builtin_amdgcn_s_barrier();

        const int par = t & 1;
        const char* ab = smem + par * 8192 + abyte;
        float4 qa = *(const float4*)(ab + au0);
        float4 qb = *(const float4*)(ab + au1);
        f16x8 af = { (f16)qa.x, (f16)qa.y, (f16)qa.z, (f16)qa.w,
                     (f16)qb.x, (f16)qb.y, (f16)qb.z, (f16)qb.w };
        const f16x8* wb = (const f16x8*)(smem + 16384 + par * 10240) + lane;
        #pragma unroll
        for (int g = 0; g < 10; ++g) {
            f16x8 bf = wb[g * 64];
            acc[g] = __builtin_amdgcn_mfma_f32_16x16x32_f16(af, bf, acc[g], 0, 0, 0);
        }

        asm volatile("s_waitcnt lgkmcnt(0)" ::: "memory");
        __builtin_amdgcn_sched_barrier(0);
        __builtin_amdgcn_s_barrier();
        if (t < 30) STAGE((t + 2 + koff) & 31, par);
    }

    // gates(+bias) -> swizzled LDS exchange
    #pragma unroll
    for (int g = 0; g < 10; ++g) {
        float bb = g_bias[g * 16 + lcol];
        #pragma unroll
        for (int r = 0; r < 4; ++r)
            gs[gaddr(wrow + l4 * 4 + r, g * 16 + lcol)] = acc[g][r] + bb;
    }
    __syncthreads();

    const int nrow = tid >> 2, sub = tid & 3;
    const int c0 = sub * 13;
    float hreg[13];
    #pragma unroll
    for (int j = 0; j < 13; ++j) {
        int c = c0 + j;
        float hv = 0.f;
        if (c < 50) {
            float iv = gs[gaddr(nrow, c)];
            float gv = gs[gaddr(nrow, 50 + c)];
            float ov = gs[gaddr(nrow, 100 + c)];
            float cv = fast_tanh(gv) / (1.f + __expf(-iv));
            hv = fast_tanh(cv) / (1.f + __expf(-ov));
        }
        hreg[j] = hv;
    }
    __syncthreads();

    #pragma unroll
    for (int j = 0; j < 13; ++j)
        hs[nrow * 72 + c0 + j] = (f16)hreg[j];
    if (sub == 3) {
        #pragma unroll
        for (int c = 52; c < 64; ++c) hs[nrow * 72 + c] = (f16)0.f;
    }
    __syncthreads();

    // h tile -> g_h (vectorized 2x16B per thread, coalesced 8KB linear)
    {
        const int hr = tid >> 2;                 // 0..63
        const int uu = (tid & 3) * 2;            // f16x8 unit 0,2,4,6
        f16x8 v0 = *(const f16x8*)(hs + hr * 72 + uu * 8);
        f16x8 v1 = *(const f16x8*)(hs + hr * 72 + uu * 8 + 8);
        *(f16x8*)(g_h + (row0 + hr) * 64 + uu * 8)     = v0;
        *(f16x8*)(g_h + (row0 + hr) * 64 + uu * 8 + 8) = v1;
    }
}

// ---- kernel B v5: identical to v4 except NONTEMPORAL out stores ------------
__global__ __launch_bounds__(1024) void lstm_lin(
    const float* __restrict__ blin, float* __restrict__ out)
{
    __shared__ __align__(16) float ls[16 * 1024];      // 64KB out-tile staging
    __shared__ __align__(16) f16 hs_l[2][16 * 72];     // h tile double buffer

    const int tid  = threadIdx.x;
    const int lane = tid & 63;
    const int wv   = tid >> 6;        // 0..15
    const int lcol = lane & 15;
    const int l4   = lane >> 4;
    const long r0  = (long)blockIdx.x * 256;

    // per-wave register-resident W2 fragments + bias (loaded ONCE)
    f16x8 w2r0[4], w2r1[4];
    float4 blr[4];
    #pragma unroll
    for (int i = 0; i < 4; ++i) {
        int ct = wv * 4 + i;
        w2r0[i] = g_w2s[ct * 128 + lane];
        w2r1[i] = g_w2s[ct * 128 + 64 + lane];
        blr[i]  = *(const float4*)(blin + ct * 16 + l4 * 4);
    }

    // stage h tile 0
    if (tid < 128) {
        int row = tid >> 3, u = tid & 7;
        *(f16x8*)(&hs_l[0][row * 72 + u * 8]) =
            *(const f16x8*)(g_h + (r0 + row) * 64 + u * 8);
    }
    __syncthreads();

    for (int rt = 0; rt < 16; ++rt) {
        const int cur = rt & 1;
        f16x8 bh0 = *(const f16x8*)(&hs_l[cur][lcol * 72 + l4 * 8]);
        f16x8 bh1 = *(const f16x8*)(&hs_l[cur][lcol * 72 + 32 + l4 * 8]);
        #pragma unroll
        for (int i = 0; i < 4; ++i) {
            int ct = wv * 4 + i;
            f32x4 o = { blr[i].x, blr[i].y, blr[i].z, blr[i].w };
            o = __builtin_amdgcn_mfma_f32_16x16x32_f16(w2r0[i], bh0, o, 0, 0, 0);
            o = __builtin_amdgcn_mfma_f32_16x16x32_f16(w2r1[i], bh1, o, 0, 0, 0);
            // D lane: out[row=lcol][ct*16 + l4*4 + r]; unit = ct*4+l4 (16B)
            int u = (ct * 4 + l4) ^ (lcol & 7);          // bank swizzle
            *(f32x4*)(ls + lcol * 1024 + u * 4) = o;
        }
        __syncthreads();
        if (rt < 15 && tid < 128) {   // stage next h tile under the copy phase
            int row = tid >> 3, u = tid & 7;
            *(f16x8*)(&hs_l[cur ^ 1][row * 72 + u * 8]) =
                *(const f16x8*)(g_h + (r0 + (rt + 1) * 16 + row) * 64 + u * 8);
        }
        {   // copy: wave wv streams its full 4KB row; NONTEMPORAL stores
            float* orow = out + (r0 + rt * 16 + wv) * 1024;
            #pragma unroll
            for (int j = 0; j < 4; ++j) {
                int u = (j * 64 + lane) ^ (wv & 7);
                f32x4 v = *(const f32x4*)(ls + wv * 1024 + u * 4);
                __builtin_nontemporal_store(v, (f32x4*)(orow + j * 256 + lane * 4));
            }
        }
        __syncthreads();
    }
}

extern "C" void kernel_launch(void* const* d_in, const int* in_sizes, int n_in,
                              void* d_out, int out_size, void* d_ws, size_t ws_size,
                              hipStream_t stream) {
    const float* x     = (const float*)d_in[0];
    const float* W_ih  = (const float*)d_in[1];
    // d_in[2] = W_hh — provably unused (h_prev = 0)
    const float* b_ih  = (const float*)d_in[3];
    const float* b_hh  = (const float*)d_in[4];
    const float* W_lin = (const float*)d_in[5];
    const float* b_lin = (const float*)d_in[6];
    float* out = (float*)d_out;

    int prep_total = W1S_ELEMS + W2S_ELEMS + 160;
    prep_kernel<<<(prep_total + 255) / 256, 256, 0, stream>>>(
        W_ih, b_ih, b_hh, W_lin);

    lstm_gates<<<1024, 256, 0, stream>>>(x);
    lstm_lin<<<256, 1024, 0, stream>>>(b_lin, out);
}